// Round 14
// baseline (646.664 us; speedup 1.0000x reference)
//
#include <hip/hip_runtime.h>

constexpr int HI = 256, WI = 256;   // reg_feat spatial
constexpr int HO = 512, WO = 512;   // upsampled spatial
constexpr int CI = 32;              // feat channels
constexpr int CK = 49;              // 7x7 unfold channels

// ---- ws layout (float offsets) --------------------------------------------
constexpr size_t OFF_WPC = 0;        // w2 frags (32x32 enc): 26*2*2*64 uint4 = 26624 f32
constexpr size_t OFF_B2P = 26624;    // padded b2 [64]
constexpr size_t OFF_WPB = 26688;    // w1 frags: 7*2*4*64 uint4 = 14336 f32
constexpr size_t OFF_B1P = 41024;    // padded b1 [64]
constexpr size_t OFF_WPA = 41088;    // wt frags: 4cls*4tap*2s*2mf*64 uint4 = 16384 f32
constexpr size_t OFF_F0  = 57472;    // f0p u32 [512][512][32]
constexpr size_t OFF_XPP = OFF_F0 + (size_t)HO * WO * CI;      // xpp u32 [258][258][32]
constexpr size_t OFF_FLP = OFF_XPP + (size_t)258 * 258 * 32;   // flowp f32 [2][518][518]

constexpr int FP_W = 518;            // padded flow row (512 + 3 + 3)
constexpr int XP_W = 258;            // padded x row (256 + 1 + 1)

using bf16x8 = __attribute__((ext_vector_type(8))) short;
using f32x4  = __attribute__((ext_vector_type(4))) float;
using f32x16 = __attribute__((ext_vector_type(16))) float;

__device__ inline unsigned bf_rne(float x) {           // fp32 -> bf16 bits (RNE)
    unsigned u = __float_as_uint(x);
    return (u + 0x7FFFu + ((u >> 16) & 1u)) >> 16;
}
__device__ inline unsigned pack_split(float v) {       // (hi<<16)|lo split-bf16
    const unsigned hi = bf_rne(v);
    const float vh = __uint_as_float(hi << 16);
    const unsigned lo = bf_rne(v - vh);
    return (hi << 16) | lo;
}

union FragU { uint4 q; bf16x8 v; unsigned u[4]; };

// v_perm selectors (validated R4-R12)
constexpr unsigned PERM_HI = 0x07060302u;
constexpr unsigned PERM_LO = 0x05040100u;

// ---------------------------------------------------------------------------
// kPP: fused padding kernel (R12 version, restored).
// ---------------------------------------------------------------------------
__global__ void kPP(const float* __restrict__ x, const float* __restrict__ flow,
                    unsigned* __restrict__ xpp, float* __restrict__ flowp)
{
    const int bid = blockIdx.x;
    if (bid < XP_W) {
        const int yp = bid;
        const int y  = yp - 1;
        for (int xpc = threadIdx.x; xpc < XP_W; xpc += 256) {
            const int xc = xpc - 1;
            uint4* dst = reinterpret_cast<uint4*>(xpp + ((size_t)yp * XP_W + xpc) * 32);
            if ((unsigned)y < 256u && (unsigned)xc < 256u) {
                const float* src = x + y * 256 + xc;
                #pragma unroll
                for (int r = 0; r < 8; ++r) {
                    uint4 q;
                    q.x = pack_split(src[(size_t)(4 * r + 0) * 65536]);
                    q.y = pack_split(src[(size_t)(4 * r + 1) * 65536]);
                    q.z = pack_split(src[(size_t)(4 * r + 2) * 65536]);
                    q.w = pack_split(src[(size_t)(4 * r + 3) * 65536]);
                    dst[r] = q;
                }
            } else {
                #pragma unroll
                for (int r = 0; r < 8; ++r) dst[r] = make_uint4(0u, 0u, 0u, 0u);
            }
        }
    } else {
        const int idx = (bid - XP_W) * 256 + threadIdx.x;
        if (idx >= 2 * FP_W * FP_W) return;
        const int p  = idx / (FP_W * FP_W);
        const int q  = idx - p * (FP_W * FP_W);
        const int hh = q / FP_W;
        const int ww = q - hh * FP_W;
        float v = 0.f;
        const int hs = hh - 3, wsx = ww - 3;
        if ((unsigned)hs < (unsigned)HO && (unsigned)wsx < (unsigned)WO)
            v = flow[p * (HO * WO) + hs * WO + wsx];
        flowp[idx] = v;
    }
}

// ---------------------------------------------------------------------------
// repack (unchanged R12): kA frags, stage-1 frags, stage-2 frags (32x32 enc).
// ---------------------------------------------------------------------------
__global__ void repack(const float* __restrict__ wt,
                       const float* __restrict__ w1, const float* __restrict__ b1,
                       const float* __restrict__ w2, const float* __restrict__ b2,
                       uint4* __restrict__ wpA, uint4* __restrict__ wpB,
                       float* __restrict__ b1p, uint4* __restrict__ wpC,
                       float* __restrict__ b2p)
{
    const int j = blockIdx.x * 256 + threadIdx.x;
    if (j < 64) {
        b2p[j] = (j < CK) ? b2[j] : 1e18f;
        b1p[j] = (j < CK) ? b1[j] : 0.f;
    }
    if (j < 4 * 4 * 2 * 2 * 64) {           // kA
        const int lane = j & 63;
        const int mf   = (j >> 6) & 1;
        const int s    = (j >> 7) & 1;
        const int tap  = (j >> 8) & 3;
        const int cls  = j >> 10;
        const int ohpar = cls >> 1, par = cls & 1;
        const int a = tap >> 1, d = tap & 1;
        const int kh = (ohpar ? 0 : 1) + 2 * a;
        const int kw = (par ? 0 : 1) + 2 * d;
        const int o = mf * 16 + (lane & 15);
        unsigned b[8];
        #pragma unroll
        for (int jj = 0; jj < 8; ++jj) {
            const int i = (lane >> 4) * 8 + jj;
            const float v = wt[((i * 32 + o) * 4 + kh) * 4 + kw];
            const unsigned hi = bf_rne(v);
            b[jj] = (s == 0) ? hi : bf_rne(v - __uint_as_float(hi << 16));
        }
        uint4 q;
        q.x = (b[1] << 16) | b[0];
        q.y = (b[3] << 16) | b[2];
        q.z = (b[5] << 16) | b[4];
        q.w = (b[7] << 16) | b[6];
        wpA[j] = q;
    }
    if (j < 7 * 2 * 4 * 64) {               // stage-1: chunk t, k = i
        const int t    = j >> 9;
        const int s    = (j >> 8) & 1;
        const int mf   = (j >> 6) & 3;
        const int lane = j & 63;
        const int o = mf * 16 + (lane & 15);
        unsigned b[8];
        #pragma unroll
        for (int jj = 0; jj < 8; ++jj) {
            const int i = (lane >> 4) * 8 + jj;
            float v = (o < CK) ? w1[o * 224 + i * 7 + t] : 0.f;
            const unsigned hi = bf_rne(v);
            b[jj] = (s == 0) ? hi : bf_rne(v - __uint_as_float(hi << 16));
        }
        uint4 q;
        q.x = (b[1] << 16) | b[0];
        q.y = (b[3] << 16) | b[2];
        q.z = (b[5] << 16) | b[4];
        q.w = (b[7] << 16) | b[6];
        wpB[((t * 2 + s) * 4 + mf) * 64 + lane] = q;
    }
    if (j < 26 * 2 * 2 * 64) {              // stage-2 32x32 encoding
        const int lane = j & 63;
        const int m    = (j >> 6) & 1;
        const int s    = (j >> 7) & 1;
        const int cc   = j >> 8;
        const int o    = m * 32 + (lane & 31);
        const int kg   = cc * 2 + (lane >> 5);
        const int oct  = kg / 7;
        const int t    = kg - 7 * oct;
        unsigned b[8];
        #pragma unroll
        for (int jj = 0; jj < 8; ++jj) {
            const int i = oct * 8 + jj;
            float v = 0.f;
            if (kg < CK && o < CK && i < CK) v = w2[o * 343 + i * 7 + t];
            const unsigned hi = bf_rne(v);
            b[jj] = (s == 0) ? hi : bf_rne(v - __uint_as_float(hi << 16));
        }
        uint4 q;
        q.x = (b[1] << 16) | b[0];
        q.y = (b[3] << 16) | b[2];
        q.z = (b[5] << 16) | b[4];
        q.w = (b[7] << 16) | b[6];
        wpC[((cc * 2 + s) * 2 + m) * 64 + lane] = q;
    }
}

// ---------------------------------------------------------------------------
// kA: ConvTranspose2d(32,32,4,s=2,p=1) via split-bf16 MFMA (unchanged R8-R12).
// ---------------------------------------------------------------------------
__global__ __launch_bounds__(256, 4)
void kA(const unsigned* __restrict__ xpp, const uint4* __restrict__ wpA,
        const float* __restrict__ bt, unsigned* __restrict__ f0p)
{
    __shared__ unsigned ep[4][64 * 36];

    const int tid  = threadIdx.x;
    const int oh   = blockIdx.x >> 1;
    const int half = blockIdx.x & 1;
    const int wv   = tid >> 6;
    const int lane = tid & 63;
    const int col  = lane & 15;
    const int g    = lane >> 4;
    const int par  = wv >> 1;
    const int n0   = half * 128 + (wv & 1) * 64;

    const int ohpar = oh & 1;
    const int kh0   = ohpar ? 0 : 1;
    const int ihA   = (oh + 1 - kh0) >> 1;
    const int cls   = ohpar * 2 + par;
    const int ioff  = par ? 2 : 1;

    f32x4 acc[2][4];
    #pragma unroll
    for (int mf = 0; mf < 2; ++mf)
        #pragma unroll
        for (int nf = 0; nf < 4; ++nf)
            acc[mf][nf] = (f32x4){0.f, 0.f, 0.f, 0.f};

    #pragma unroll
    for (int a = 0; a < 2; ++a) {
        const int rowbase = (ihA + 1 - a) * XP_W;
        #pragma unroll
        for (int d = 0; d < 2; ++d) {
            bf16x8 Bh[4], Bl[4];
            #pragma unroll
            for (int nf = 0; nf < 4; ++nf) {
                const size_t base =
                    ((size_t)(rowbase + n0 + nf * 16 + col + ioff - d)) * 32 + g * 8;
                const uint4 q0 = *reinterpret_cast<const uint4*>(xpp + base);
                const uint4 q1 = *reinterpret_cast<const uint4*>(xpp + base + 4);
                const unsigned u[8] = {q0.x, q0.y, q0.z, q0.w, q1.x, q1.y, q1.z, q1.w};
                FragU fh, fl;
                #pragma unroll
                for (int r = 0; r < 4; ++r) {
                    fh.u[r] = __builtin_amdgcn_perm(u[2 * r + 1], u[2 * r], PERM_HI);
                    fl.u[r] = __builtin_amdgcn_perm(u[2 * r + 1], u[2 * r], PERM_LO);
                }
                Bh[nf] = fh.v;
                Bl[nf] = fl.v;
            }
            const int tap = a * 2 + d;
            #pragma unroll
            for (int mf = 0; mf < 2; ++mf) {
                FragU ah, al;
                ah.q = wpA[(((cls * 4 + tap) * 2 + 0) * 2 + mf) * 64 + lane];
                al.q = wpA[(((cls * 4 + tap) * 2 + 1) * 2 + mf) * 64 + lane];
                #pragma unroll
                for (int nf = 0; nf < 4; ++nf) {
                    acc[mf][nf] = __builtin_amdgcn_mfma_f32_16x16x32_bf16(ah.v, Bh[nf], acc[mf][nf], 0, 0, 0);
                    acc[mf][nf] = __builtin_amdgcn_mfma_f32_16x16x32_bf16(ah.v, Bl[nf], acc[mf][nf], 0, 0, 0);
                    acc[mf][nf] = __builtin_amdgcn_mfma_f32_16x16x32_bf16(al.v, Bh[nf], acc[mf][nf], 0, 0, 0);
                }
            }
        }
    }

    unsigned* myep = ep[wv];
    #pragma unroll
    for (int mf = 0; mf < 2; ++mf)
        #pragma unroll
        for (int r = 0; r < 4; ++r) {
            const int ch = mf * 16 + g * 4 + r;
            const float bv = bt[ch];
            #pragma unroll
            for (int nf = 0; nf < 4; ++nf)
                myep[(nf * 16 + col) * 36 + ch] = pack_split(acc[mf][nf][r] + bv);
        }

    const int ow = 2 * (n0 + lane) + par;
    uint4* dst = reinterpret_cast<uint4*>(f0p + ((size_t)oh * WO + ow) * 32);
    const uint4* src = reinterpret_cast<const uint4*>(myep + lane * 36);
    #pragma unroll
    for (int u = 0; u < 8; ++u) dst[u] = src[u];
}

// ---------------------------------------------------------------------------
// kBC: FUSED stage B + stage C, now 512 THREADS (8 waves) per 128-px strip.
// Same per-block work as R12; waves/CU 16 -> 32 (latency hiding). Stage 1:
// wave wv owns frag wv (wave 0 also frag 8). Stage 2 (32x32x16): wave
// (wv_m = wv>>2, wv_n = wv&3) computes 32 ch x 32 px, single f32x16 acc.
// Epilogue: single-sided publish (validated R13), adapted to 2x4 split.
// ---------------------------------------------------------------------------
__global__ __launch_bounds__(512, 8)
void kBC(const unsigned* __restrict__ f0p, const uint4* __restrict__ wpB,
         const float* __restrict__ b1p, const uint4* __restrict__ wpC,
         const float* __restrict__ b2p, const float* __restrict__ flowp,
         float* __restrict__ out)
{
    __shared__ uint4 Lh4[134 * 7];          // hi-plane, rows of 7 uint4 (56 ch)
    __shared__ uint4 Ll4[134 * 7];          // lo-plane
    __shared__ float gm[2][128];            // per-m-half per-pixel min (both publish)
    __shared__ float dvp1[128];             // wv_m==1 partials only
    __shared__ float sxp1[128];
    __shared__ float syp1[128];
    unsigned* Lh = reinterpret_cast<unsigned*>(Lh4);
    unsigned* Ll = reinterpret_cast<unsigned*>(Ll4);

    // bijective XCD swizzle: 2048 blocks = 8 XCDs x 256 contiguous
    const int bid = ((blockIdx.x & 7) << 8) + (blockIdx.x >> 3);
    const int h   = bid >> 2;
    const int w0  = (bid & 3) << 7;

    const int tid  = threadIdx.x;
    const int wv   = tid >> 6;              // 0..7
    const int lane = tid & 63;
    const int col  = lane & 15;
    const int g    = lane >> 4;

    // ---- stage 1: f1 row h, cols w0-3 .. w0+140 (9 frags over 8 waves) -----
    const int nfr = (wv == 0) ? 2 : 1;
    const int fid0 = wv, fid1 = 8;

    f32x4 acc1[2][4];
    #pragma unroll
    for (int fi = 0; fi < 2; ++fi)
        #pragma unroll
        for (int mf = 0; mf < 4; ++mf)
            acc1[fi][mf] = (f32x4){0.f, 0.f, 0.f, 0.f};

    #pragma unroll
    for (int t = 0; t < 7; ++t) {
        const int hr = h + t - 3;
        if ((unsigned)hr < (unsigned)HO) {
            FragU ah[4], al[4];
            #pragma unroll
            for (int mf = 0; mf < 4; ++mf) {
                ah[mf].q = wpB[((t * 2 + 0) * 4 + mf) * 64 + lane];
                al[mf].q = wpB[((t * 2 + 1) * 4 + mf) * 64 + lane];
            }
            #pragma unroll
            for (int fi = 0; fi < 2; ++fi) {
                if (fi < nfr) {
                    const int f  = (fi == 0) ? fid0 : fid1;
                    const int wc = w0 - 3 + f * 16 + col;
                    const int wcc = min(max(wc, 0), WO - 1);
                    const bool valid = ((unsigned)wc < (unsigned)WO);
                    const size_t base = ((size_t)hr * WO + wcc) * 32 + g * 8;
                    uint4 q0 = *reinterpret_cast<const uint4*>(f0p + base);
                    uint4 q1 = *reinterpret_cast<const uint4*>(f0p + base + 4);
                    if (!valid) { q0 = make_uint4(0,0,0,0); q1 = make_uint4(0,0,0,0); }
                    const unsigned u[8] = {q0.x, q0.y, q0.z, q0.w, q1.x, q1.y, q1.z, q1.w};
                    FragU fh, fl;
                    #pragma unroll
                    for (int r = 0; r < 4; ++r) {
                        fh.u[r] = __builtin_amdgcn_perm(u[2 * r + 1], u[2 * r], PERM_HI);
                        fl.u[r] = __builtin_amdgcn_perm(u[2 * r + 1], u[2 * r], PERM_LO);
                    }
                    #pragma unroll
                    for (int mf = 0; mf < 4; ++mf) {
                        acc1[fi][mf] = __builtin_amdgcn_mfma_f32_16x16x32_bf16(ah[mf].v, fh.v, acc1[fi][mf], 0, 0, 0);
                        acc1[fi][mf] = __builtin_amdgcn_mfma_f32_16x16x32_bf16(ah[mf].v, fl.v, acc1[fi][mf], 0, 0, 0);
                        acc1[fi][mf] = __builtin_amdgcn_mfma_f32_16x16x32_bf16(al[mf].v, fh.v, acc1[fi][mf], 0, 0, 0);
                    }
                }
            }
        }
    }

    // write f1 row into transposed planes; out-of-image columns store ZERO.
    #pragma unroll
    for (int fi = 0; fi < 2; ++fi) {
        if (fi < nfr) {
            const int f = (fi == 0) ? fid0 : fid1;
            const int q = f * 16 + col;
            const int wc = w0 - 3 + q;
            const bool vcol = ((unsigned)wc < (unsigned)WO);
            if (q < 134) {
                #pragma unroll
                for (int mf = 0; mf < 4; ++mf) {
                    if (mf < 3 || g < 2) {          // ch 56..63 don't exist
                        const int chb = mf * 16 + g * 4;
                        unsigned hh[4], ll[4];
                        #pragma unroll
                        for (int r = 0; r < 4; ++r) {
                            const float v = vcol ? (acc1[fi][mf][r] + b1p[chb + r]) : 0.f;
                            hh[r] = bf_rne(v);
                            ll[r] = bf_rne(v - __uint_as_float(hh[r] << 16));
                        }
                        const int ip = mf * 8 + g * 2;
                        Lh[q * 28 + ip]     = (hh[1] << 16) | hh[0];
                        Lh[q * 28 + ip + 1] = (hh[3] << 16) | hh[2];
                        Ll[q * 28 + ip]     = (ll[1] << 16) | ll[0];
                        Ll[q * 28 + ip + 1] = (ll[3] << 16) | ll[2];
                    }
                }
            }
        }
    }
    __syncthreads();

    // ---- stage 2 (32x32x16): wave (wv_m, wv_n) = 32 ch x 32 px -------------
    const int wv_m = wv >> 2;               // 0..1 (channel half)
    const int wv_n = wv & 3;                // 0..3 (pixel quarter)
    const int lh   = lane >> 5;             // k-half selector
    const int p32  = lane & 31;             // pixel within 32-frag

    f32x16 acc2;
    #pragma unroll
    for (int r = 0; r < 16; ++r) acc2[r] = 0.f;

    #pragma unroll
    for (int cc = 0; cc < 25; ++cc) {       // cc=25 would be all-pad (kg 50,51)
        const int kg  = cc * 2 + lh;
        const int oct = (kg * 37) >> 8;     // kg/7 for kg<=51
        const int t   = kg - 7 * oct;
        FragU ah, al;
        ah.q = wpC[((cc * 2 + 0) * 2 + wv_m) * 64 + lane];
        al.q = wpC[((cc * 2 + 1) * 2 + wv_m) * 64 + lane];
        const int bq = (wv_n * 32 + p32 + t) * 7 + oct;
        FragU bh, bl;
        bh.q = Lh4[bq];
        bl.q = Ll4[bq];
        acc2 = __builtin_amdgcn_mfma_f32_32x32x16_bf16(ah.v, bh.v, acc2, 0, 0, 0);
        acc2 = __builtin_amdgcn_mfma_f32_32x32x16_bf16(ah.v, bl.v, acc2, 0, 0, 0);
        acc2 = __builtin_amdgcn_mfma_f32_32x32x16_bf16(al.v, bh.v, acc2, 0, 0, 0);
    }

    // ---- epilogue: sq, cross-wave min, exp-weighted flow average -----------
    // C/D: col(px) = lane&31, row(ch in 32) = (reg&3) + 8*(reg>>2) + 4*lh
    float bb2[16];
    #pragma unroll
    for (int reg = 0; reg < 16; ++reg) {
        const int ch = wv_m * 32 + lh * 4 + (reg & 3) + 8 * (reg >> 2);
        bb2[reg] = b2p[ch];
    }

    #pragma unroll
    for (int reg = 0; reg < 16; ++reg) {
        const float fv = acc2[reg] + bb2[reg];
        acc2[reg] = fv * fv;
    }

    {
        float m = acc2[0];
        #pragma unroll
        for (int reg = 1; reg < 16; ++reg) m = fminf(m, acc2[reg]);
        m = fminf(m, __shfl_xor(m, 32));
        if (lane < 32) gm[wv_m][wv_n * 32 + lane] = m;
    }
    __syncthreads();

    const int px = wv_n * 32 + p32;         // pixel within the 128-strip
    const float M2 = fminf(gm[0][px], gm[1][px]);

    const float* fpx = flowp + (size_t)h * FP_W + (w0 + px);
    const float* fpy = fpx + (size_t)FP_W * FP_W;
    float dvr = 0.f, sxr = 0.f, syr = 0.f;

    #pragma unroll
    for (int reg = 0; reg < 16; ++reg) {
        const int ch = wv_m * 32 + lh * 4 + (reg & 3) + 8 * (reg >> 2);
        int ki = (ch * 37) >> 8;            // floor(ch/7) for ch<64
        int kj = ch - 7 * ki;
        ki = min(ki, 6);                    // pad channels: d==0, clamp keeps in-bounds
        kj = min(kj, 6);
        const int off = ki * FP_W + kj;
        const float d = __expf(M2 - acc2[reg]);
        dvr += d;
        sxr += d * fpx[off];
        syr += d * fpy[off];
    }

    dvr += __shfl_xor(dvr, 32);
    sxr += __shfl_xor(sxr, 32);
    syr += __shfl_xor(syr, 32);

    if (wv_m == 1 && lane < 32) {
        dvp1[px & 127] = dvr;               // px = wv_n*32 + lane here
        sxp1[px & 127] = sxr;
        syp1[px & 127] = syr;
    }
    __syncthreads();

    if (wv_m == 0 && lane < 32) {
        const float D = dvr + dvp1[px];
        const float X = sxr + sxp1[px];
        const float Y = syr + syp1[px];
        const int w = w0 + px;
        out[(size_t)h * WO + w]                   = X / D;
        out[(size_t)HO * WO + (size_t)h * WO + w] = Y / D;
    }
}

// ---------------------------------------------------------------------------
extern "C" void kernel_launch(void* const* d_in, const int* in_sizes, int n_in,
                              void* d_out, int out_size, void* d_ws, size_t ws_size,
                              hipStream_t stream) {
    const float* reg_feat = (const float*)d_in[0];
    const float* flow     = (const float*)d_in[1];
    const float* wt       = (const float*)d_in[2];
    const float* bt       = (const float*)d_in[3];
    const float* w1       = (const float*)d_in[4];
    const float* b1       = (const float*)d_in[5];
    const float* w2       = (const float*)d_in[6];
    const float* b2       = (const float*)d_in[7];
    float* out = (float*)d_out;
    (void)in_sizes; (void)n_in; (void)out_size; (void)ws_size;

    float*    ws    = (float*)d_ws;
    uint4*    wpC   = (uint4*)(ws + OFF_WPC);
    float*    b2p   = ws + OFF_B2P;
    uint4*    wpB   = (uint4*)(ws + OFF_WPB);
    float*    b1p   = ws + OFF_B1P;
    uint4*    wpA   = (uint4*)(ws + OFF_WPA);
    unsigned* f0p   = (unsigned*)(ws + OFF_F0);
    unsigned* xpp   = (unsigned*)(ws + OFF_XPP);
    float*    flowp = ws + OFF_FLP;

    repack<<<26, 256, 0, stream>>>(wt, w1, b1, w2, b2, wpA, wpB, b1p, wpC, b2p);

    const int padBlocks = XP_W + (2 * FP_W * FP_W + 255) / 256;
    for (int b = 0; b < 4; ++b) {
        const float* xb  = reg_feat + (size_t)b * CI * HI * WI;
        const float* flb = flow     + (size_t)b * 2 * HO * WO;
        float*       ob  = out      + (size_t)b * 2 * HO * WO;
        kPP<<<padBlocks, 256, 0, stream>>>(xb, flb, xpp, flowp);
        kA<<<1024, 256, 0, stream>>>(xpp, wpA, bt, f0p);
        kBC<<<2048, 512, 0, stream>>>(f0p, wpB, b1p, wpC, b2p, flowp, ob);
    }
}

// Round 15
// 476.174 us; speedup vs baseline: 1.3580x; 1.3580x over previous
//
#include <hip/hip_runtime.h>

constexpr int HI = 256, WI = 256;   // reg_feat spatial
constexpr int HO = 512, WO = 512;   // upsampled spatial
constexpr int CI = 32;              // feat channels
constexpr int CK = 49;              // 7x7 unfold channels

// ---- ws layout (float offsets) --------------------------------------------
constexpr size_t OFF_WPC = 0;        // w2 frags: 13*2*4*64 uint4 = 26624 f32
constexpr size_t OFF_B2P = 26624;    // padded b2 [64]
constexpr size_t OFF_WPB = 26688;    // w1 frags: 7*2*4*64 uint4 = 14336 f32
constexpr size_t OFF_B1P = 41024;    // padded b1 [64]
constexpr size_t OFF_WPA = 41088;    // wt frags: 4cls*4tap*2s*2mf*64 uint4 = 16384 f32
constexpr size_t OFF_F0  = 57472;    // f0p u32 [512][512][32]
constexpr size_t OFF_XPP = OFF_F0 + (size_t)HO * WO * CI;      // xpp u32 [258][258][32]
constexpr size_t OFF_FLP = OFF_XPP + (size_t)258 * 258 * 32;   // flowp f32 [2][518][518]

constexpr int FP_W = 518;            // padded flow row (512 + 3 + 3)
constexpr int XP_W = 258;            // padded x row (256 + 1 + 1)

using bf16x8 = __attribute__((ext_vector_type(8))) short;
using f32x4  = __attribute__((ext_vector_type(4))) float;

__device__ inline unsigned bf_rne(float x) {           // fp32 -> bf16 bits (RNE)
    unsigned u = __float_as_uint(x);
    return (u + 0x7FFFu + ((u >> 16) & 1u)) >> 16;
}
__device__ inline unsigned pack_split(float v) {       // (hi<<16)|lo split-bf16
    const unsigned hi = bf_rne(v);
    const float vh = __uint_as_float(hi << 16);
    const unsigned lo = bf_rne(v - vh);
    return (hi << 16) | lo;
}

union FragU { uint4 q; bf16x8 v; unsigned u[4]; };

// v_perm selectors (validated R4-R12)
constexpr unsigned PERM_HI = 0x07060302u;
constexpr unsigned PERM_LO = 0x05040100u;

// ---------------------------------------------------------------------------
// kXP: x[32][256][256] f32 -> xpp[yp][xp][i] packed split-bf16 u32, 0-border.
// ---------------------------------------------------------------------------
__global__ void kXP(const float* __restrict__ x, unsigned* __restrict__ xpp)
{
    const int yp = blockIdx.x;          // 0..257
    const int y  = yp - 1;
    for (int xpc = threadIdx.x; xpc < XP_W; xpc += 256) {
        const int xc = xpc - 1;
        uint4* dst = reinterpret_cast<uint4*>(xpp + ((size_t)yp * XP_W + xpc) * 32);
        if ((unsigned)y < 256u && (unsigned)xc < 256u) {
            const float* src = x + y * 256 + xc;
            #pragma unroll
            for (int r = 0; r < 8; ++r) {
                uint4 q;
                q.x = pack_split(src[(size_t)(4 * r + 0) * 65536]);
                q.y = pack_split(src[(size_t)(4 * r + 1) * 65536]);
                q.z = pack_split(src[(size_t)(4 * r + 2) * 65536]);
                q.w = pack_split(src[(size_t)(4 * r + 3) * 65536]);
                dst[r] = q;
            }
        } else {
            #pragma unroll
            for (int r = 0; r < 8; ++r) dst[r] = make_uint4(0u, 0u, 0u, 0u);
        }
    }
}

// ---------------------------------------------------------------------------
// repack (R11 version): kA frags, stage-1 frags, stage-2 frags (16x16 enc).
// ---------------------------------------------------------------------------
__global__ void repack(const float* __restrict__ wt,
                       const float* __restrict__ w1, const float* __restrict__ b1,
                       const float* __restrict__ w2, const float* __restrict__ b2,
                       uint4* __restrict__ wpA, uint4* __restrict__ wpB,
                       float* __restrict__ b1p, uint4* __restrict__ wpC,
                       float* __restrict__ b2p)
{
    const int j = blockIdx.x * 256 + threadIdx.x;
    if (j < 64) {
        b2p[j] = (j < CK) ? b2[j] : 1e18f;
        b1p[j] = (j < CK) ? b1[j] : 0.f;
    }
    if (j < 4 * 4 * 2 * 2 * 64) {           // kA
        const int lane = j & 63;
        const int mf   = (j >> 6) & 1;
        const int s    = (j >> 7) & 1;
        const int tap  = (j >> 8) & 3;
        const int cls  = j >> 10;
        const int ohpar = cls >> 1, par = cls & 1;
        const int a = tap >> 1, d = tap & 1;
        const int kh = (ohpar ? 0 : 1) + 2 * a;
        const int kw = (par ? 0 : 1) + 2 * d;
        const int o = mf * 16 + (lane & 15);
        unsigned b[8];
        #pragma unroll
        for (int jj = 0; jj < 8; ++jj) {
            const int i = (lane >> 4) * 8 + jj;
            const float v = wt[((i * 32 + o) * 4 + kh) * 4 + kw];
            const unsigned hi = bf_rne(v);
            b[jj] = (s == 0) ? hi : bf_rne(v - __uint_as_float(hi << 16));
        }
        uint4 q;
        q.x = (b[1] << 16) | b[0];
        q.y = (b[3] << 16) | b[2];
        q.z = (b[5] << 16) | b[4];
        q.w = (b[7] << 16) | b[6];
        wpA[j] = q;
    }
    if (j < 7 * 2 * 4 * 64) {               // stage-1: chunk t, k = i
        const int t    = j >> 9;
        const int s    = (j >> 8) & 1;
        const int mf   = (j >> 6) & 3;
        const int lane = j & 63;
        const int o = mf * 16 + (lane & 15);
        unsigned b[8];
        #pragma unroll
        for (int jj = 0; jj < 8; ++jj) {
            const int i = (lane >> 4) * 8 + jj;
            float v = (o < CK) ? w1[o * 224 + i * 7 + t] : 0.f;
            const unsigned hi = bf_rne(v);
            b[jj] = (s == 0) ? hi : bf_rne(v - __uint_as_float(hi << 16));
        }
        uint4 q;
        q.x = (b[1] << 16) | b[0];
        q.y = (b[3] << 16) | b[2];
        q.z = (b[5] << 16) | b[4];
        q.w = (b[7] << 16) | b[6];
        wpB[((t * 2 + s) * 4 + mf) * 64 + lane] = q;
    }
    if (j < 13 * 2 * 4 * 64) {              // stage-2: kg=4c+g -> (oct,t); i=oct*8+jj
        const int c    = j >> 9;
        const int s    = (j >> 8) & 1;
        const int mf   = (j >> 6) & 3;
        const int lane = j & 63;
        const int o   = mf * 16 + (lane & 15);
        const int kg  = 4 * c + (lane >> 4);
        const int oct = kg / 7;
        const int t   = kg - 7 * oct;
        unsigned b[8];
        #pragma unroll
        for (int jj = 0; jj < 8; ++jj) {
            const int i = oct * 8 + jj;
            float v = 0.f;
            if (kg < CK && o < CK && i < CK) v = w2[o * 343 + i * 7 + t];
            const unsigned hi = bf_rne(v);
            b[jj] = (s == 0) ? hi : bf_rne(v - __uint_as_float(hi << 16));
        }
        uint4 q;
        q.x = (b[1] << 16) | b[0];
        q.y = (b[3] << 16) | b[2];
        q.z = (b[5] << 16) | b[4];
        q.w = (b[7] << 16) | b[6];
        wpC[((c * 2 + s) * 4 + mf) * 64 + lane] = q;
    }
}

// ---------------------------------------------------------------------------
// kA: ConvTranspose2d via split-bf16 MFMA (R11 body). Blocks >= 1024 instead
// pad flow into flowp (folded former kPP part-2; saves 4 dispatches and
// overlaps the memory-bound padding with kA's MFMA work).
// ---------------------------------------------------------------------------
__global__ __launch_bounds__(256, 4)
void kA(const unsigned* __restrict__ xpp, const uint4* __restrict__ wpA,
        const float* __restrict__ bt, unsigned* __restrict__ f0p,
        const float* __restrict__ flow, float* __restrict__ flowp)
{
    __shared__ unsigned ep[4][64 * 36];

    if (blockIdx.x >= 1024) {               // flow-padding part
        const int idx = (blockIdx.x - 1024) * 256 + threadIdx.x;
        if (idx < 2 * FP_W * FP_W) {
            const int p  = idx / (FP_W * FP_W);
            const int q  = idx - p * (FP_W * FP_W);
            const int hh = q / FP_W;
            const int ww = q - hh * FP_W;
            float v = 0.f;
            const int hs = hh - 3, wsx = ww - 3;
            if ((unsigned)hs < (unsigned)HO && (unsigned)wsx < (unsigned)WO)
                v = flow[p * (HO * WO) + hs * WO + wsx];
            flowp[idx] = v;
        }
        return;
    }

    const int tid  = threadIdx.x;
    const int oh   = blockIdx.x >> 1;
    const int half = blockIdx.x & 1;
    const int wv   = tid >> 6;
    const int lane = tid & 63;
    const int col  = lane & 15;
    const int g    = lane >> 4;
    const int par  = wv >> 1;
    const int n0   = half * 128 + (wv & 1) * 64;

    const int ohpar = oh & 1;
    const int kh0   = ohpar ? 0 : 1;
    const int ihA   = (oh + 1 - kh0) >> 1;
    const int cls   = ohpar * 2 + par;
    const int ioff  = par ? 2 : 1;

    f32x4 acc[2][4];
    #pragma unroll
    for (int mf = 0; mf < 2; ++mf)
        #pragma unroll
        for (int nf = 0; nf < 4; ++nf)
            acc[mf][nf] = (f32x4){0.f, 0.f, 0.f, 0.f};

    #pragma unroll
    for (int a = 0; a < 2; ++a) {
        const int rowbase = (ihA + 1 - a) * XP_W;
        #pragma unroll
        for (int d = 0; d < 2; ++d) {
            bf16x8 Bh[4], Bl[4];
            #pragma unroll
            for (int nf = 0; nf < 4; ++nf) {
                const size_t base =
                    ((size_t)(rowbase + n0 + nf * 16 + col + ioff - d)) * 32 + g * 8;
                const uint4 q0 = *reinterpret_cast<const uint4*>(xpp + base);
                const uint4 q1 = *reinterpret_cast<const uint4*>(xpp + base + 4);
                const unsigned u[8] = {q0.x, q0.y, q0.z, q0.w, q1.x, q1.y, q1.z, q1.w};
                FragU fh, fl;
                #pragma unroll
                for (int r = 0; r < 4; ++r) {
                    fh.u[r] = __builtin_amdgcn_perm(u[2 * r + 1], u[2 * r], PERM_HI);
                    fl.u[r] = __builtin_amdgcn_perm(u[2 * r + 1], u[2 * r], PERM_LO);
                }
                Bh[nf] = fh.v;
                Bl[nf] = fl.v;
            }
            const int tap = a * 2 + d;
            #pragma unroll
            for (int mf = 0; mf < 2; ++mf) {
                FragU ah, al;
                ah.q = wpA[(((cls * 4 + tap) * 2 + 0) * 2 + mf) * 64 + lane];
                al.q = wpA[(((cls * 4 + tap) * 2 + 1) * 2 + mf) * 64 + lane];
                #pragma unroll
                for (int nf = 0; nf < 4; ++nf) {
                    acc[mf][nf] = __builtin_amdgcn_mfma_f32_16x16x32_bf16(ah.v, Bh[nf], acc[mf][nf], 0, 0, 0);
                    acc[mf][nf] = __builtin_amdgcn_mfma_f32_16x16x32_bf16(ah.v, Bl[nf], acc[mf][nf], 0, 0, 0);
                    acc[mf][nf] = __builtin_amdgcn_mfma_f32_16x16x32_bf16(al.v, Bh[nf], acc[mf][nf], 0, 0, 0);
                }
            }
        }
    }

    unsigned* myep = ep[wv];
    #pragma unroll
    for (int mf = 0; mf < 2; ++mf)
        #pragma unroll
        for (int r = 0; r < 4; ++r) {
            const int ch = mf * 16 + g * 4 + r;
            const float bv = bt[ch];
            #pragma unroll
            for (int nf = 0; nf < 4; ++nf)
                myep[(nf * 16 + col) * 36 + ch] = pack_split(acc[mf][nf][r] + bv);
        }

    const int ow = 2 * (n0 + lane) + par;
    uint4* dst = reinterpret_cast<uint4*>(f0p + ((size_t)oh * WO + ow) * 32);
    const uint4* src = reinterpret_cast<const uint4*>(myep + lane * 36);
    #pragma unroll
    for (int u = 0; u < 8; ++u) dst[u] = src[u];
}

// ---------------------------------------------------------------------------
// kBC: FUSED stage B + stage C — R11 body (known-good, 90.5 us), plus ONE
// change: s_setprio(1) around the stage-2 MFMA loop (T5: co-resident blocks
// are at different phases — stage-1 VMEM vs stage-2 MFMA — so priority gives
// the MFMA-issuing waves arbitration wins).
// ---------------------------------------------------------------------------
__global__ __launch_bounds__(256, 4)
void kBC(const unsigned* __restrict__ f0p, const uint4* __restrict__ wpB,
         const float* __restrict__ b1p, const uint4* __restrict__ wpC,
         const float* __restrict__ b2p, const float* __restrict__ flowp,
         float* __restrict__ out)
{
    __shared__ uint4 Lh4[134 * 7];          // hi-plane, rows of 7 uint4 (56 ch)
    __shared__ uint4 Ll4[134 * 7];          // lo-plane
    __shared__ float gm[4][128];            // per-wave per-pixel min partials
    __shared__ float dvp[4][128];           // per-wave softmax partials
    __shared__ float sxp[4][128];
    __shared__ float syp[4][128];
    unsigned* Lh = reinterpret_cast<unsigned*>(Lh4);
    unsigned* Ll = reinterpret_cast<unsigned*>(Ll4);

    // bijective XCD swizzle: 2048 blocks = 8 XCDs x 256 contiguous
    const int bid = ((blockIdx.x & 7) << 8) + (blockIdx.x >> 3);
    const int h   = bid >> 2;
    const int w0  = (bid & 3) << 7;

    const int tid  = threadIdx.x;
    const int wv   = tid >> 6;
    const int lane = tid & 63;
    const int col  = lane & 15;
    const int g    = lane >> 4;

    // ---- stage 1: f1 row h, cols w0-3 .. w0+140 (9 frags of 16) ------------
    const int nfr = (wv == 3) ? 3 : 2;
    const int fid0 = wv, fid1 = wv + 4, fid2 = 8;

    f32x4 acc1[3][4];
    #pragma unroll
    for (int fi = 0; fi < 3; ++fi)
        #pragma unroll
        for (int mf = 0; mf < 4; ++mf)
            acc1[fi][mf] = (f32x4){0.f, 0.f, 0.f, 0.f};

    #pragma unroll
    for (int t = 0; t < 7; ++t) {
        const int hr = h + t - 3;
        if ((unsigned)hr < (unsigned)HO) {
            FragU ah[4], al[4];
            #pragma unroll
            for (int mf = 0; mf < 4; ++mf) {
                ah[mf].q = wpB[((t * 2 + 0) * 4 + mf) * 64 + lane];
                al[mf].q = wpB[((t * 2 + 1) * 4 + mf) * 64 + lane];
            }
            #pragma unroll
            for (int fi = 0; fi < 3; ++fi) {
                if (fi < nfr) {
                    const int f  = (fi == 0) ? fid0 : (fi == 1) ? fid1 : fid2;
                    const int wc = w0 - 3 + f * 16 + col;
                    const int wcc = min(max(wc, 0), WO - 1);
                    const bool valid = ((unsigned)wc < (unsigned)WO);
                    const size_t base = ((size_t)hr * WO + wcc) * 32 + g * 8;
                    uint4 q0 = *reinterpret_cast<const uint4*>(f0p + base);
                    uint4 q1 = *reinterpret_cast<const uint4*>(f0p + base + 4);
                    if (!valid) { q0 = make_uint4(0,0,0,0); q1 = make_uint4(0,0,0,0); }
                    const unsigned u[8] = {q0.x, q0.y, q0.z, q0.w, q1.x, q1.y, q1.z, q1.w};
                    FragU fh, fl;
                    #pragma unroll
                    for (int r = 0; r < 4; ++r) {
                        fh.u[r] = __builtin_amdgcn_perm(u[2 * r + 1], u[2 * r], PERM_HI);
                        fl.u[r] = __builtin_amdgcn_perm(u[2 * r + 1], u[2 * r], PERM_LO);
                    }
                    #pragma unroll
                    for (int mf = 0; mf < 4; ++mf) {
                        acc1[fi][mf] = __builtin_amdgcn_mfma_f32_16x16x32_bf16(ah[mf].v, fh.v, acc1[fi][mf], 0, 0, 0);
                        acc1[fi][mf] = __builtin_amdgcn_mfma_f32_16x16x32_bf16(ah[mf].v, fl.v, acc1[fi][mf], 0, 0, 0);
                        acc1[fi][mf] = __builtin_amdgcn_mfma_f32_16x16x32_bf16(al[mf].v, fh.v, acc1[fi][mf], 0, 0, 0);
                    }
                }
            }
        }
    }

    // write f1 row into transposed planes; out-of-image columns store ZERO.
    #pragma unroll
    for (int fi = 0; fi < 3; ++fi) {
        if (fi < nfr) {
            const int f = (fi == 0) ? fid0 : (fi == 1) ? fid1 : fid2;
            const int q = f * 16 + col;
            const int wc = w0 - 3 + q;
            const bool vcol = ((unsigned)wc < (unsigned)WO);
            if (q < 134) {
                #pragma unroll
                for (int mf = 0; mf < 4; ++mf) {
                    if (mf < 3 || g < 2) {          // ch 56..63 don't exist
                        const int chb = mf * 16 + g * 4;
                        unsigned hh[4], ll[4];
                        #pragma unroll
                        for (int r = 0; r < 4; ++r) {
                            const float v = vcol ? (acc1[fi][mf][r] + b1p[chb + r]) : 0.f;
                            hh[r] = bf_rne(v);
                            ll[r] = bf_rne(v - __uint_as_float(hh[r] << 16));
                        }
                        const int ip = mf * 8 + g * 2;
                        Lh[q * 28 + ip]     = (hh[1] << 16) | hh[0];
                        Lh[q * 28 + ip + 1] = (hh[3] << 16) | hh[2];
                        Ll[q * 28 + ip]     = (ll[1] << 16) | ll[0];
                        Ll[q * 28 + ip + 1] = (ll[3] << 16) | ll[2];
                    }
                }
            }
        }
    }
    __syncthreads();

    // ---- stage 2: wave wv = mf; all 128 px (nf=0..7) -----------------------
    const int mf2 = wv;
    f32x4 acc[8];
    #pragma unroll
    for (int nf = 0; nf < 8; ++nf)
        acc[nf] = (f32x4){0.f, 0.f, 0.f, 0.f};

    __builtin_amdgcn_s_setprio(1);
    #pragma unroll
    for (int c = 0; c < 13; ++c) {
        const int kg  = 4 * c + g;
        const int oct = (kg * 37) >> 8;     // kg/7 for kg<=51
        const int t   = kg - 7 * oct;
        FragU ah, al;
        ah.q = wpC[((c * 2 + 0) * 4 + mf2) * 64 + lane];
        al.q = wpC[((c * 2 + 1) * 4 + mf2) * 64 + lane];
        const int bqb = (col + t) * 7 + oct;
        #pragma unroll
        for (int nf = 0; nf < 8; ++nf) {
            FragU bh, bl;
            bh.q = Lh4[bqb + nf * 112];     // +16 px * 7 uint4
            bl.q = Ll4[bqb + nf * 112];
            acc[nf] = __builtin_amdgcn_mfma_f32_16x16x32_bf16(ah.v, bh.v, acc[nf], 0, 0, 0);
            acc[nf] = __builtin_amdgcn_mfma_f32_16x16x32_bf16(ah.v, bl.v, acc[nf], 0, 0, 0);
            acc[nf] = __builtin_amdgcn_mfma_f32_16x16x32_bf16(al.v, bh.v, acc[nf], 0, 0, 0);
        }
    }
    __builtin_amdgcn_s_setprio(0);

    // ---- epilogue: sq, cross-wave min, exp-weighted flow average -----------
    float bb2[4];
    #pragma unroll
    for (int r = 0; r < 4; ++r)
        bb2[r] = b2p[mf2 * 16 + g * 4 + r];

    #pragma unroll
    for (int nf = 0; nf < 8; ++nf)
        #pragma unroll
        for (int r = 0; r < 4; ++r) {
            const float fv = acc[nf][r] + bb2[r];
            acc[nf][r] = fv * fv;
        }

    #pragma unroll
    for (int nf = 0; nf < 8; ++nf) {
        float m = fminf(fminf(acc[nf][0], acc[nf][1]), fminf(acc[nf][2], acc[nf][3]));
        m = fminf(m, __shfl_xor(m, 16));
        m = fminf(m, __shfl_xor(m, 32));
        if (lane < 16) gm[wv][nf * 16 + lane] = m;
    }
    __syncthreads();

    float M[8];
    #pragma unroll
    for (int nf = 0; nf < 8; ++nf)
        M[nf] = fminf(fminf(gm[0][nf * 16 + col], gm[1][nf * 16 + col]),
                      fminf(gm[2][nf * 16 + col], gm[3][nf * 16 + col]));

    const float* fpx = flowp + (size_t)h * FP_W + (w0 + col);
    const float* fpy = fpx + (size_t)FP_W * FP_W;
    float dv[8], sx[8], sy[8];
    #pragma unroll
    for (int nf = 0; nf < 8; ++nf) { dv[nf] = 0.f; sx[nf] = 0.f; sy[nf] = 0.f; }

    #pragma unroll
    for (int r = 0; r < 4; ++r) {
        const int ch = mf2 * 16 + g * 4 + r;
        int ki = (ch * 37) >> 8;            // floor(ch/7) for ch<64
        int kj = ch - 7 * ki;
        ki = min(ki, 6);                    // pad channels: d==0, clamp for safety
        kj = min(kj, 6);
        const int off = ki * FP_W + kj;
        #pragma unroll
        for (int nf = 0; nf < 8; ++nf) {
            const float d = __expf(M[nf] - acc[nf][r]);
            dv[nf] += d;
            sx[nf] += d * fpx[off + nf * 16];
            sy[nf] += d * fpy[off + nf * 16];
        }
    }

    #pragma unroll
    for (int nf = 0; nf < 8; ++nf) {
        float d = dv[nf], x = sx[nf], y = sy[nf];
        d += __shfl_xor(d, 16);  x += __shfl_xor(x, 16);  y += __shfl_xor(y, 16);
        d += __shfl_xor(d, 32);  x += __shfl_xor(x, 32);  y += __shfl_xor(y, 32);
        if (lane < 16) {
            dvp[wv][nf * 16 + lane] = d;
            sxp[wv][nf * 16 + lane] = x;
            syp[wv][nf * 16 + lane] = y;
        }
    }
    __syncthreads();

    if (tid < 128) {
        const float D = dvp[0][tid] + dvp[1][tid] + dvp[2][tid] + dvp[3][tid];
        const float X = sxp[0][tid] + sxp[1][tid] + sxp[2][tid] + sxp[3][tid];
        const float Y = syp[0][tid] + syp[1][tid] + syp[2][tid] + syp[3][tid];
        const int w = w0 + tid;
        out[(size_t)h * WO + w]                   = X / D;
        out[(size_t)HO * WO + (size_t)h * WO + w] = Y / D;
    }
}

// ---------------------------------------------------------------------------
extern "C" void kernel_launch(void* const* d_in, const int* in_sizes, int n_in,
                              void* d_out, int out_size, void* d_ws, size_t ws_size,
                              hipStream_t stream) {
    const float* reg_feat = (const float*)d_in[0];
    const float* flow     = (const float*)d_in[1];
    const float* wt       = (const float*)d_in[2];
    const float* bt       = (const float*)d_in[3];
    const float* w1       = (const float*)d_in[4];
    const float* b1       = (const float*)d_in[5];
    const float* w2       = (const float*)d_in[6];
    const float* b2       = (const float*)d_in[7];
    float* out = (float*)d_out;
    (void)in_sizes; (void)n_in; (void)out_size; (void)ws_size;

    float*    ws    = (float*)d_ws;
    uint4*    wpC   = (uint4*)(ws + OFF_WPC);
    float*    b2p   = ws + OFF_B2P;
    uint4*    wpB   = (uint4*)(ws + OFF_WPB);
    float*    b1p   = ws + OFF_B1P;
    uint4*    wpA   = (uint4*)(ws + OFF_WPA);
    unsigned* f0p   = (unsigned*)(ws + OFF_F0);
    unsigned* xpp   = (unsigned*)(ws + OFF_XPP);
    float*    flowp = ws + OFF_FLP;

    repack<<<26, 256, 0, stream>>>(wt, w1, b1, w2, b2, wpA, wpB, b1p, wpC, b2p);

    const int flowBlocks = (2 * FP_W * FP_W + 255) / 256;   // 2097
    for (int b = 0; b < 4; ++b) {
        const float* xb  = reg_feat + (size_t)b * CI * HI * WI;
        const float* flb = flow     + (size_t)b * 2 * HO * WO;
        float*       ob  = out      + (size_t)b * 2 * HO * WO;
        kXP<<<XP_W, 256, 0, stream>>>(xb, xpp);
        kA<<<1024 + flowBlocks, 256, 0, stream>>>(xpp, wpA, bt, f0p, flb, flowp);
        kBC<<<2048, 256, 0, stream>>>(f0p, wpB, b1p, wpC, b2p, flowp, ob);
    }
}

// Round 16
// 408.403 us; speedup vs baseline: 1.5834x; 1.1659x over previous
//
#include <hip/hip_runtime.h>

constexpr int HI = 256, WI = 256;   // reg_feat spatial
constexpr int HO = 512, WO = 512;   // upsampled spatial
constexpr int CI = 32;              // feat channels
constexpr int CK = 49;              // 7x7 unfold channels

// ---- ws layout (float offsets) --------------------------------------------
constexpr size_t OFF_WPC = 0;        // w2 frags: 13*2*4*64 uint4 = 26624 f32
constexpr size_t OFF_B2P = 26624;    // padded b2 [64]
constexpr size_t OFF_WPB = 26688;    // w1 frags: 7*2*4*64 uint4 = 14336 f32
constexpr size_t OFF_B1P = 41024;    // padded b1 [64]
constexpr size_t OFF_WPA = 41088;    // wt frags: 4cls*4tap*2s*2mf*64 uint4 = 16384 f32
constexpr size_t OFF_F0  = 57472;    // f0h,f0l bf16 planes [512][512][32] each
constexpr size_t OFF_XPP = OFF_F0 + (size_t)HO * WO * CI;      // xph,xpl planes
constexpr size_t OFF_FLP = OFF_XPP + (size_t)258 * 258 * 32;   // flowp f32 [2][518][518]

constexpr int FP_W = 518;            // padded flow row (512 + 3 + 3)
constexpr int XP_W = 258;            // padded x row (256 + 1 + 1)

using bf16x8 = __attribute__((ext_vector_type(8))) short;
using f32x4  = __attribute__((ext_vector_type(4))) float;

__device__ inline unsigned bf_rne(float x) {           // fp32 -> bf16 bits (RNE)
    unsigned u = __float_as_uint(x);
    return (u + 0x7FFFu + ((u >> 16) & 1u)) >> 16;
}

union FragU { uint4 q; bf16x8 v; unsigned u[4]; };

// ---------------------------------------------------------------------------
// kPP: fused padding kernel. Part 1 (bid<258): x -> SEPARATE hi/lo bf16
// planes xph/xpl [258][258][32] (zero border). Part 2: flowp zero-padded.
// Separate planes remove all v_perm repack at the consumers (kA).
// ---------------------------------------------------------------------------
__global__ void kPP(const float* __restrict__ x, const float* __restrict__ flow,
                    unsigned short* __restrict__ xph, unsigned short* __restrict__ xpl,
                    float* __restrict__ flowp)
{
    const int bid = blockIdx.x;
    if (bid < XP_W) {
        const int yp = bid;
        const int y  = yp - 1;
        for (int xpc = threadIdx.x; xpc < XP_W; xpc += 256) {
            const int xc = xpc - 1;
            const size_t po = ((size_t)yp * XP_W + xpc) * 32;   // ushort index
            uint4* dh = reinterpret_cast<uint4*>(xph + po);
            uint4* dl = reinterpret_cast<uint4*>(xpl + po);
            if ((unsigned)y < 256u && (unsigned)xc < 256u) {
                const float* src = x + y * 256 + xc;
                unsigned hw[16], lw[16];
                #pragma unroll
                for (int c2 = 0; c2 < 16; ++c2) {
                    const float v0 = src[(size_t)(2 * c2) * 65536];
                    const float v1 = src[(size_t)(2 * c2 + 1) * 65536];
                    const unsigned h0 = bf_rne(v0), h1 = bf_rne(v1);
                    const unsigned l0 = bf_rne(v0 - __uint_as_float(h0 << 16));
                    const unsigned l1 = bf_rne(v1 - __uint_as_float(h1 << 16));
                    hw[c2] = (h1 << 16) | h0;
                    lw[c2] = (l1 << 16) | l0;
                }
                const uint4* hq = reinterpret_cast<const uint4*>(hw);
                const uint4* lq = reinterpret_cast<const uint4*>(lw);
                #pragma unroll
                for (int r = 0; r < 4; ++r) { dh[r] = hq[r]; dl[r] = lq[r]; }
            } else {
                #pragma unroll
                for (int r = 0; r < 4; ++r) {
                    dh[r] = make_uint4(0u, 0u, 0u, 0u);
                    dl[r] = make_uint4(0u, 0u, 0u, 0u);
                }
            }
        }
    } else {
        const int idx = (bid - XP_W) * 256 + threadIdx.x;
        if (idx >= 2 * FP_W * FP_W) return;
        const int p  = idx / (FP_W * FP_W);
        const int q  = idx - p * (FP_W * FP_W);
        const int hh = q / FP_W;
        const int ww = q - hh * FP_W;
        float v = 0.f;
        const int hs = hh - 3, wsx = ww - 3;
        if ((unsigned)hs < (unsigned)HO && (unsigned)wsx < (unsigned)WO)
            v = flow[p * (HO * WO) + hs * WO + wsx];
        flowp[idx] = v;
    }
}

// ---------------------------------------------------------------------------
// repack (R11 version, unchanged): kA frags, stage-1 frags, stage-2 frags.
// ---------------------------------------------------------------------------
__global__ void repack(const float* __restrict__ wt,
                       const float* __restrict__ w1, const float* __restrict__ b1,
                       const float* __restrict__ w2, const float* __restrict__ b2,
                       uint4* __restrict__ wpA, uint4* __restrict__ wpB,
                       float* __restrict__ b1p, uint4* __restrict__ wpC,
                       float* __restrict__ b2p)
{
    const int j = blockIdx.x * 256 + threadIdx.x;
    if (j < 64) {
        b2p[j] = (j < CK) ? b2[j] : 1e18f;
        b1p[j] = (j < CK) ? b1[j] : 0.f;
    }
    if (j < 4 * 4 * 2 * 2 * 64) {           // kA
        const int lane = j & 63;
        const int mf   = (j >> 6) & 1;
        const int s    = (j >> 7) & 1;
        const int tap  = (j >> 8) & 3;
        const int cls  = j >> 10;
        const int ohpar = cls >> 1, par = cls & 1;
        const int a = tap >> 1, d = tap & 1;
        const int kh = (ohpar ? 0 : 1) + 2 * a;
        const int kw = (par ? 0 : 1) + 2 * d;
        const int o = mf * 16 + (lane & 15);
        unsigned b[8];
        #pragma unroll
        for (int jj = 0; jj < 8; ++jj) {
            const int i = (lane >> 4) * 8 + jj;
            const float v = wt[((i * 32 + o) * 4 + kh) * 4 + kw];
            const unsigned hi = bf_rne(v);
            b[jj] = (s == 0) ? hi : bf_rne(v - __uint_as_float(hi << 16));
        }
        uint4 q;
        q.x = (b[1] << 16) | b[0];
        q.y = (b[3] << 16) | b[2];
        q.z = (b[5] << 16) | b[4];
        q.w = (b[7] << 16) | b[6];
        wpA[j] = q;
    }
    if (j < 7 * 2 * 4 * 64) {               // stage-1: chunk t, k = i
        const int t    = j >> 9;
        const int s    = (j >> 8) & 1;
        const int mf   = (j >> 6) & 3;
        const int lane = j & 63;
        const int o = mf * 16 + (lane & 15);
        unsigned b[8];
        #pragma unroll
        for (int jj = 0; jj < 8; ++jj) {
            const int i = (lane >> 4) * 8 + jj;
            float v = (o < CK) ? w1[o * 224 + i * 7 + t] : 0.f;
            const unsigned hi = bf_rne(v);
            b[jj] = (s == 0) ? hi : bf_rne(v - __uint_as_float(hi << 16));
        }
        uint4 q;
        q.x = (b[1] << 16) | b[0];
        q.y = (b[3] << 16) | b[2];
        q.z = (b[5] << 16) | b[4];
        q.w = (b[7] << 16) | b[6];
        wpB[((t * 2 + s) * 4 + mf) * 64 + lane] = q;
    }
    if (j < 13 * 2 * 4 * 64) {              // stage-2: kg=4c+g -> (oct,t); i=oct*8+jj
        const int c    = j >> 9;
        const int s    = (j >> 8) & 1;
        const int mf   = (j >> 6) & 3;
        const int lane = j & 63;
        const int o   = mf * 16 + (lane & 15);
        const int kg  = 4 * c + (lane >> 4);
        const int oct = kg / 7;
        const int t   = kg - 7 * oct;
        unsigned b[8];
        #pragma unroll
        for (int jj = 0; jj < 8; ++jj) {
            const int i = oct * 8 + jj;
            float v = 0.f;
            if (kg < CK && o < CK && i < CK) v = w2[o * 343 + i * 7 + t];
            const unsigned hi = bf_rne(v);
            b[jj] = (s == 0) ? hi : bf_rne(v - __uint_as_float(hi << 16));
        }
        uint4 q;
        q.x = (b[1] << 16) | b[0];
        q.y = (b[3] << 16) | b[2];
        q.z = (b[5] << 16) | b[4];
        q.w = (b[7] << 16) | b[6];
        wpC[((c * 2 + s) * 4 + mf) * 64 + lane] = q;
    }
}

// ---------------------------------------------------------------------------
// kA: ConvTranspose2d via split-bf16 MFMA. B-frags now DIRECT uint4 loads
// from the hi/lo planes (zero v_perm). Epilogue writes hi/lo planes of f0.
// ---------------------------------------------------------------------------
__global__ __launch_bounds__(256, 4)
void kA(const unsigned short* __restrict__ xph, const unsigned short* __restrict__ xpl,
        const uint4* __restrict__ wpA, const float* __restrict__ bt,
        unsigned short* __restrict__ f0h, unsigned short* __restrict__ f0l)
{
    __shared__ unsigned ep[4][64 * 36];     // [px][hi0..15 | lo16..31 | pad]

    const int tid  = threadIdx.x;
    const int oh   = blockIdx.x >> 1;
    const int half = blockIdx.x & 1;
    const int wv   = tid >> 6;
    const int lane = tid & 63;
    const int col  = lane & 15;
    const int g    = lane >> 4;
    const int par  = wv >> 1;
    const int n0   = half * 128 + (wv & 1) * 64;

    const int ohpar = oh & 1;
    const int kh0   = ohpar ? 0 : 1;
    const int ihA   = (oh + 1 - kh0) >> 1;
    const int cls   = ohpar * 2 + par;
    const int ioff  = par ? 2 : 1;

    f32x4 acc[2][4];
    #pragma unroll
    for (int mf = 0; mf < 2; ++mf)
        #pragma unroll
        for (int nf = 0; nf < 4; ++nf)
            acc[mf][nf] = (f32x4){0.f, 0.f, 0.f, 0.f};

    #pragma unroll
    for (int a = 0; a < 2; ++a) {
        const int rowbase = (ihA + 1 - a) * XP_W;
        #pragma unroll
        for (int d = 0; d < 2; ++d) {
            bf16x8 Bh[4], Bl[4];
            #pragma unroll
            for (int nf = 0; nf < 4; ++nf) {
                const size_t base =
                    ((size_t)(rowbase + n0 + nf * 16 + col + ioff - d)) * 32 + g * 8;
                FragU fh, fl;
                fh.q = *reinterpret_cast<const uint4*>(xph + base);
                fl.q = *reinterpret_cast<const uint4*>(xpl + base);
                Bh[nf] = fh.v;
                Bl[nf] = fl.v;
            }
            const int tap = a * 2 + d;
            #pragma unroll
            for (int mf = 0; mf < 2; ++mf) {
                FragU ah, al;
                ah.q = wpA[(((cls * 4 + tap) * 2 + 0) * 2 + mf) * 64 + lane];
                al.q = wpA[(((cls * 4 + tap) * 2 + 1) * 2 + mf) * 64 + lane];
                #pragma unroll
                for (int nf = 0; nf < 4; ++nf) {
                    acc[mf][nf] = __builtin_amdgcn_mfma_f32_16x16x32_bf16(ah.v, Bh[nf], acc[mf][nf], 0, 0, 0);
                    acc[mf][nf] = __builtin_amdgcn_mfma_f32_16x16x32_bf16(ah.v, Bl[nf], acc[mf][nf], 0, 0, 0);
                    acc[mf][nf] = __builtin_amdgcn_mfma_f32_16x16x32_bf16(al.v, Bh[nf], acc[mf][nf], 0, 0, 0);
                }
            }
        }
    }

    // epilogue: bias, split, LDS transpose (wave-private), plane stores
    unsigned* myep = ep[wv];
    #pragma unroll
    for (int mf = 0; mf < 2; ++mf)
        #pragma unroll
        for (int nf = 0; nf < 4; ++nf) {
            unsigned hh[4], ll[4];
            #pragma unroll
            for (int r = 0; r < 4; ++r) {
                const int ch = mf * 16 + g * 4 + r;
                const float v = acc[mf][nf][r] + bt[ch];
                hh[r] = bf_rne(v);
                ll[r] = bf_rne(v - __uint_as_float(hh[r] << 16));
            }
            unsigned* row = myep + (nf * 16 + col) * 36;
            const int cp = mf * 8 + g * 2;
            row[cp]          = (hh[1] << 16) | hh[0];
            row[cp + 1]      = (hh[3] << 16) | hh[2];
            row[16 + cp]     = (ll[1] << 16) | ll[0];
            row[16 + cp + 1] = (ll[3] << 16) | ll[2];
        }
    // same-wave LDS RAW: compiler orders via lgkmcnt; no barrier needed

    const int ow = 2 * (n0 + lane) + par;
    const size_t po = ((size_t)oh * WO + ow) * 32;   // ushort index
    uint4* dh = reinterpret_cast<uint4*>(f0h + po);
    uint4* dl = reinterpret_cast<uint4*>(f0l + po);
    const uint4* sh = reinterpret_cast<const uint4*>(myep + lane * 36);
    const uint4* sl = reinterpret_cast<const uint4*>(myep + lane * 36 + 16);
    #pragma unroll
    for (int u = 0; u < 4; ++u) { dh[u] = sh[u]; dl[u] = sl[u]; }
}

// ---------------------------------------------------------------------------
// kBC: FUSED stage B + stage C — R11 body; stage-1 B-frags now DIRECT plane
// loads (zero v_perm). Everything else identical to the validated R11 kernel.
// ---------------------------------------------------------------------------
__global__ __launch_bounds__(256, 4)
void kBC(const unsigned short* __restrict__ f0h, const unsigned short* __restrict__ f0l,
         const uint4* __restrict__ wpB, const float* __restrict__ b1p,
         const uint4* __restrict__ wpC, const float* __restrict__ b2p,
         const float* __restrict__ flowp, float* __restrict__ out)
{
    __shared__ uint4 Lh4[134 * 7];          // hi-plane, rows of 7 uint4 (56 ch)
    __shared__ uint4 Ll4[134 * 7];          // lo-plane
    __shared__ float gm[4][128];            // per-wave per-pixel min partials
    __shared__ float dvp[4][128];           // per-wave softmax partials
    __shared__ float sxp[4][128];
    __shared__ float syp[4][128];
    unsigned* Lh = reinterpret_cast<unsigned*>(Lh4);
    unsigned* Ll = reinterpret_cast<unsigned*>(Ll4);

    // bijective XCD swizzle: 2048 blocks = 8 XCDs x 256 contiguous
    const int bid = ((blockIdx.x & 7) << 8) + (blockIdx.x >> 3);
    const int h   = bid >> 2;
    const int w0  = (bid & 3) << 7;

    const int tid  = threadIdx.x;
    const int wv   = tid >> 6;
    const int lane = tid & 63;
    const int col  = lane & 15;
    const int g    = lane >> 4;

    // ---- stage 1: f1 row h, cols w0-3 .. w0+140 (9 frags of 16) ------------
    const int nfr = (wv == 3) ? 3 : 2;
    const int fid0 = wv, fid1 = wv + 4, fid2 = 8;

    f32x4 acc1[3][4];
    #pragma unroll
    for (int fi = 0; fi < 3; ++fi)
        #pragma unroll
        for (int mf = 0; mf < 4; ++mf)
            acc1[fi][mf] = (f32x4){0.f, 0.f, 0.f, 0.f};

    #pragma unroll
    for (int t = 0; t < 7; ++t) {
        const int hr = h + t - 3;
        if ((unsigned)hr < (unsigned)HO) {
            FragU ah[4], al[4];
            #pragma unroll
            for (int mf = 0; mf < 4; ++mf) {
                ah[mf].q = wpB[((t * 2 + 0) * 4 + mf) * 64 + lane];
                al[mf].q = wpB[((t * 2 + 1) * 4 + mf) * 64 + lane];
            }
            #pragma unroll
            for (int fi = 0; fi < 3; ++fi) {
                if (fi < nfr) {
                    const int f  = (fi == 0) ? fid0 : (fi == 1) ? fid1 : fid2;
                    const int wc = w0 - 3 + f * 16 + col;
                    const int wcc = min(max(wc, 0), WO - 1);
                    const bool valid = ((unsigned)wc < (unsigned)WO);
                    const size_t base = ((size_t)hr * WO + wcc) * 32 + g * 8;
                    FragU fh, fl;
                    fh.q = *reinterpret_cast<const uint4*>(f0h + base);
                    fl.q = *reinterpret_cast<const uint4*>(f0l + base);
                    if (!valid) {
                        fh.q = make_uint4(0u, 0u, 0u, 0u);
                        fl.q = make_uint4(0u, 0u, 0u, 0u);
                    }
                    #pragma unroll
                    for (int mf = 0; mf < 4; ++mf) {
                        acc1[fi][mf] = __builtin_amdgcn_mfma_f32_16x16x32_bf16(ah[mf].v, fh.v, acc1[fi][mf], 0, 0, 0);
                        acc1[fi][mf] = __builtin_amdgcn_mfma_f32_16x16x32_bf16(ah[mf].v, fl.v, acc1[fi][mf], 0, 0, 0);
                        acc1[fi][mf] = __builtin_amdgcn_mfma_f32_16x16x32_bf16(al[mf].v, fh.v, acc1[fi][mf], 0, 0, 0);
                    }
                }
            }
        }
    }

    // write f1 row into transposed planes; out-of-image columns store ZERO.
    #pragma unroll
    for (int fi = 0; fi < 3; ++fi) {
        if (fi < nfr) {
            const int f = (fi == 0) ? fid0 : (fi == 1) ? fid1 : fid2;
            const int q = f * 16 + col;
            const int wc = w0 - 3 + q;
            const bool vcol = ((unsigned)wc < (unsigned)WO);
            if (q < 134) {
                #pragma unroll
                for (int mf = 0; mf < 4; ++mf) {
                    if (mf < 3 || g < 2) {          // ch 56..63 don't exist
                        const int chb = mf * 16 + g * 4;
                        unsigned hh[4], ll[4];
                        #pragma unroll
                        for (int r = 0; r < 4; ++r) {
                            const float v = vcol ? (acc1[fi][mf][r] + b1p[chb + r]) : 0.f;
                            hh[r] = bf_rne(v);
                            ll[r] = bf_rne(v - __uint_as_float(hh[r] << 16));
                        }
                        const int ip = mf * 8 + g * 2;
                        Lh[q * 28 + ip]     = (hh[1] << 16) | hh[0];
                        Lh[q * 28 + ip + 1] = (hh[3] << 16) | hh[2];
                        Ll[q * 28 + ip]     = (ll[1] << 16) | ll[0];
                        Ll[q * 28 + ip + 1] = (ll[3] << 16) | ll[2];
                    }
                }
            }
        }
    }
    __syncthreads();

    // ---- stage 2: wave wv = mf; all 128 px (nf=0..7) -----------------------
    const int mf2 = wv;
    f32x4 acc[8];
    #pragma unroll
    for (int nf = 0; nf < 8; ++nf)
        acc[nf] = (f32x4){0.f, 0.f, 0.f, 0.f};

    #pragma unroll
    for (int c = 0; c < 13; ++c) {
        const int kg  = 4 * c + g;
        const int oct = (kg * 37) >> 8;     // kg/7 for kg<=51
        const int t   = kg - 7 * oct;
        FragU ah, al;
        ah.q = wpC[((c * 2 + 0) * 4 + mf2) * 64 + lane];
        al.q = wpC[((c * 2 + 1) * 4 + mf2) * 64 + lane];
        const int bqb = (col + t) * 7 + oct;
        #pragma unroll
        for (int nf = 0; nf < 8; ++nf) {
            FragU bh, bl;
            bh.q = Lh4[bqb + nf * 112];     // +16 px * 7 uint4
            bl.q = Ll4[bqb + nf * 112];
            acc[nf] = __builtin_amdgcn_mfma_f32_16x16x32_bf16(ah.v, bh.v, acc[nf], 0, 0, 0);
            acc[nf] = __builtin_amdgcn_mfma_f32_16x16x32_bf16(ah.v, bl.v, acc[nf], 0, 0, 0);
            acc[nf] = __builtin_amdgcn_mfma_f32_16x16x32_bf16(al.v, bh.v, acc[nf], 0, 0, 0);
        }
    }

    // ---- epilogue: sq, cross-wave min, exp-weighted flow average -----------
    float bb2[4];
    #pragma unroll
    for (int r = 0; r < 4; ++r)
        bb2[r] = b2p[mf2 * 16 + g * 4 + r];

    #pragma unroll
    for (int nf = 0; nf < 8; ++nf)
        #pragma unroll
        for (int r = 0; r < 4; ++r) {
            const float fv = acc[nf][r] + bb2[r];
            acc[nf][r] = fv * fv;
        }

    #pragma unroll
    for (int nf = 0; nf < 8; ++nf) {
        float m = fminf(fminf(acc[nf][0], acc[nf][1]), fminf(acc[nf][2], acc[nf][3]));
        m = fminf(m, __shfl_xor(m, 16));
        m = fminf(m, __shfl_xor(m, 32));
        if (lane < 16) gm[wv][nf * 16 + lane] = m;
    }
    __syncthreads();

    float M[8];
    #pragma unroll
    for (int nf = 0; nf < 8; ++nf)
        M[nf] = fminf(fminf(gm[0][nf * 16 + col], gm[1][nf * 16 + col]),
                      fminf(gm[2][nf * 16 + col], gm[3][nf * 16 + col]));

    const float* fpx = flowp + (size_t)h * FP_W + (w0 + col);
    const float* fpy = fpx + (size_t)FP_W * FP_W;
    float dv[8], sx[8], sy[8];
    #pragma unroll
    for (int nf = 0; nf < 8; ++nf) { dv[nf] = 0.f; sx[nf] = 0.f; sy[nf] = 0.f; }

    #pragma unroll
    for (int r = 0; r < 4; ++r) {
        const int ch = mf2 * 16 + g * 4 + r;
        int ki = (ch * 37) >> 8;            // floor(ch/7) for ch<64
        int kj = ch - 7 * ki;
        ki = min(ki, 6);                    // pad channels: d==0, clamp for safety
        kj = min(kj, 6);
        const int off = ki * FP_W + kj;
        #pragma unroll
        for (int nf = 0; nf < 8; ++nf) {
            const float d = __expf(M[nf] - acc[nf][r]);
            dv[nf] += d;
            sx[nf] += d * fpx[off + nf * 16];
            sy[nf] += d * fpy[off + nf * 16];
        }
    }

    #pragma unroll
    for (int nf = 0; nf < 8; ++nf) {
        float d = dv[nf], x = sx[nf], y = sy[nf];
        d += __shfl_xor(d, 16);  x += __shfl_xor(x, 16);  y += __shfl_xor(y, 16);
        d += __shfl_xor(d, 32);  x += __shfl_xor(x, 32);  y += __shfl_xor(y, 32);
        if (lane < 16) {
            dvp[wv][nf * 16 + lane] = d;
            sxp[wv][nf * 16 + lane] = x;
            syp[wv][nf * 16 + lane] = y;
        }
    }
    __syncthreads();

    if (tid < 128) {
        const float D = dvp[0][tid] + dvp[1][tid] + dvp[2][tid] + dvp[3][tid];
        const float X = sxp[0][tid] + sxp[1][tid] + sxp[2][tid] + sxp[3][tid];
        const float Y = syp[0][tid] + syp[1][tid] + syp[2][tid] + syp[3][tid];
        const int w = w0 + tid;
        out[(size_t)h * WO + w]                   = X / D;
        out[(size_t)HO * WO + (size_t)h * WO + w] = Y / D;
    }
}

// ---------------------------------------------------------------------------
extern "C" void kernel_launch(void* const* d_in, const int* in_sizes, int n_in,
                              void* d_out, int out_size, void* d_ws, size_t ws_size,
                              hipStream_t stream) {
    const float* reg_feat = (const float*)d_in[0];
    const float* flow     = (const float*)d_in[1];
    const float* wt       = (const float*)d_in[2];
    const float* bt       = (const float*)d_in[3];
    const float* w1       = (const float*)d_in[4];
    const float* b1       = (const float*)d_in[5];
    const float* w2       = (const float*)d_in[6];
    const float* b2       = (const float*)d_in[7];
    float* out = (float*)d_out;
    (void)in_sizes; (void)n_in; (void)out_size; (void)ws_size;

    float*          ws   = (float*)d_ws;
    uint4*          wpC  = (uint4*)(ws + OFF_WPC);
    float*          b2p  = ws + OFF_B2P;
    uint4*          wpB  = (uint4*)(ws + OFF_WPB);
    float*          b1p  = ws + OFF_B1P;
    uint4*          wpA  = (uint4*)(ws + OFF_WPA);
    unsigned short* f0h  = (unsigned short*)(ws + OFF_F0);
    unsigned short* f0l  = f0h + (size_t)HO * WO * CI;
    unsigned short* xph  = (unsigned short*)(ws + OFF_XPP);
    unsigned short* xpl  = xph + (size_t)XP_W * XP_W * 32;
    float*          flowp = ws + OFF_FLP;

    repack<<<26, 256, 0, stream>>>(wt, w1, b1, w2, b2, wpA, wpB, b1p, wpC, b2p);

    const int padBlocks = XP_W + (2 * FP_W * FP_W + 255) / 256;
    for (int b = 0; b < 4; ++b) {
        const float* xb  = reg_feat + (size_t)b * CI * HI * WI;
        const float* flb = flow     + (size_t)b * 2 * HO * WO;
        float*       ob  = out      + (size_t)b * 2 * HO * WO;
        kPP<<<padBlocks, 256, 0, stream>>>(xb, flb, xph, xpl, flowp);
        kA<<<1024, 256, 0, stream>>>(xph, xpl, wpA, bt, f0h, f0l);
        kBC<<<2048, 256, 0, stream>>>(f0h, f0l, wpB, b1p, wpC, b2p, flowp, ob);
    }
}